// Round 4
// baseline (534.204 us; speedup 1.0000x reference)
//
#include <hip/hip_runtime.h>
#include <hip/hip_bf16.h>

typedef __attribute__((ext_vector_type(8))) short  short8;
typedef __attribute__((ext_vector_type(4))) short  short4v;
typedef __attribute__((ext_vector_type(4))) float  f32x4;

#define ALPHA 0.1f

__device__ __forceinline__ unsigned short f2bf(float f) {
    unsigned int u = __float_as_uint(f);
    u = (u + 0x7FFFu + ((u >> 16) & 1u)) >> 16;   // RNE
    return (unsigned short)u;
}

__device__ __forceinline__ f32x4 mfma16(short8 a, short8 b, f32x4 c) {
    return __builtin_amdgcn_mfma_f32_16x16x32_bf16(a, b, c, 0, 0, 0);
}

// ---- ws layout (bytes) ----
// P:     float  [4][256][128]  = x@W1x + y@W1y + b1        (524288 B)
// W1rT:  ushort [128][64]      W1rT[h][e] = W1[96+e][h]    (16384 B)
// W2T:   ushort [128][128]     W2T[n][k]  = W2[k][n]       (32768 B)
// W3T:   ushort [64][128]      W3T[e][h]  = W3[h][e]       (16384 B)
// ATTC:  ushort [4][256][256]                              (524288 B)
// ATTQ:  ushort [4][256][256]                              (524288 B)
#define WS_P     0u
#define WS_W1RT  524288u
#define WS_W2T   540672u
#define WS_W3T   573440u
#define WS_ATTC  589824u
#define WS_ATTQ  1114112u

__global__ __launch_bounds__(256) void prep_kernel(
    const float* __restrict__ x, const float* __restrict__ y,
    const float* __restrict__ cat, const float* __restrict__ qat,
    const float* __restrict__ W1, const float* __restrict__ b1,
    const float* __restrict__ W2, const float* __restrict__ W3,
    unsigned char* __restrict__ ws)
{
    const unsigned int blk = blockIdx.x, tid = threadIdx.x;
    float* P = (float*)(ws + WS_P);
    unsigned short* W1rT = (unsigned short*)(ws + WS_W1RT);
    unsigned short* W2T  = (unsigned short*)(ws + WS_W2T);
    unsigned short* W3T  = (unsigned short*)(ws + WS_W3T);
    unsigned short* AC   = (unsigned short*)(ws + WS_ATTC);
    unsigned short* AQ   = (unsigned short*)(ws + WS_ATTQ);

    if (blk < 512u) {                          // P[b*256+j][h], 131072 threads
        unsigned int t = blk * 256u + tid;
        unsigned int h = t & 127u, bj = t >> 7;
        float acc = b1[h];
        const float* xp = x + bj * 64u;
        const float* yp = y + bj * 32u;
        #pragma unroll 8
        for (int d = 0; d < 64; ++d) acc += xp[d] * W1[d * 128 + h];
        #pragma unroll 8
        for (int d = 0; d < 32; ++d) acc += yp[d] * W1[(64 + d) * 128 + h];
        P[t] = acc;
    } else if (blk < 544u) {                   // W1rT (8192)
        unsigned int w = (blk - 512u) * 256u + tid;
        unsigned int h = w >> 6, e = w & 63u;
        W1rT[w] = f2bf(W1[(96u + e) * 128u + h]);
    } else if (blk < 608u) {                   // W2T (16384)
        unsigned int w = (blk - 544u) * 256u + tid;
        unsigned int n = w >> 7, k2 = w & 127u;
        W2T[w] = f2bf(W2[k2 * 128u + n]);
    } else if (blk < 640u) {                   // W3T (8192)
        unsigned int w = (blk - 608u) * 256u + tid;
        unsigned int e = w >> 7, h = w & 127u;
        W3T[w] = f2bf(W3[h * 64u + e]);
    } else if (blk < 896u) {                   // ATTC (65536 x4)
        unsigned int w = (blk - 640u) * 256u + tid;
        f32x4 v = *(const f32x4*)(cat + 4u * w);
        short4v o;
        #pragma unroll
        for (int i = 0; i < 4; ++i) o[i] = (short)f2bf(v[i]);
        *(short4v*)(AC + 4u * w) = o;
    } else {                                   // ATTQ (65536 x4)
        unsigned int w = (blk - 896u) * 256u + tid;
        f32x4 v = *(const f32x4*)(qat + 4u * w);
        short4v o;
        #pragma unroll
        for (int i = 0; i < 4; ++i) o[i] = (short)f2bf(v[i]);
        *(short4v*)(AQ + 4u * w) = o;
    }
}

// One block per (b,k). 4 waves. MLP phases computed transposed (D[h][j])
// so each lane's 4 acc values are 4 consecutive h -> ds_write_b64 + float4
// bias loads. Attention computed as D[e][i] (A=U^T from LDS, B=att map) so
// each lane's 4 acc values are 4 consecutive e -> float4 global load/store.
__global__ __launch_bounds__(256, 3) void fused_kernel(
    const float* __restrict__ rc, const float* __restrict__ rq,
    const float* __restrict__ b2, const float* __restrict__ b3,
    const unsigned char* __restrict__ ws,
    float* __restrict__ out_rc, float* __restrict__ out_rq)
{
    const float* P = (const float*)(ws + WS_P);
    const unsigned short* W1rT = (const unsigned short*)(ws + WS_W1RT);
    const unsigned short* W2T  = (const unsigned short*)(ws + WS_W2T);
    const unsigned short* W3T  = (const unsigned short*)(ws + WS_W3T);
    const unsigned short* AC   = (const unsigned short*)(ws + WS_ATTC);
    const unsigned short* AQ   = (const unsigned short*)(ws + WS_ATTQ);

    __shared__ unsigned short sH[64][136];    // H strip, 272B row = 16B mult
    __shared__ unsigned short sUT[64][264];   // U^T [e][j], 528B row = 16B mult

    const int tid  = threadIdx.x;
    const int lane = tid & 63;
    const int wid  = tid >> 6;
    const int l15  = lane & 15;
    const int lg   = lane >> 4;
    const int b    = blockIdx.y;
    const int k    = blockIdx.x;

    const size_t bk = (size_t)(b * 256 + k);
    const float* rcb = rc + bk * (256 * 64);
    const float* rqb = rq + bk * (256 * 64);
    const float* Pb  = P + b * (256 * 128);

    float b3v[4];
    #pragma unroll
    for (int ct = 0; ct < 4; ++ct) b3v[ct] = b3[16 * ct + l15];

    // ---------------- MLP: 4 chunks of 64 rows ----------------
    for (int jc = 0; jc < 4; ++jc) {
        const int jrow = jc * 64 + 16 * wid + l15;   // this lane's j row

        // phase A: H1^T[h][j] = relu(W1r^T x rc^T + P^T), K=64
        f32x4 accA[8];
        #pragma unroll
        for (int mt = 0; mt < 8; ++mt) accA[mt] = (f32x4)0.f;
        #pragma unroll
        for (int ks = 0; ks < 2; ++ks) {
            const float* ap = rcb + jrow * 64 + 32 * ks + 8 * lg;
            f32x4 a0 = *(const f32x4*)ap;
            f32x4 a1 = *(const f32x4*)(ap + 4);
            short8 bfrag;
            #pragma unroll
            for (int i = 0; i < 4; ++i) {
                bfrag[i]     = (short)f2bf(a0[i]);
                bfrag[4 + i] = (short)f2bf(a1[i]);
            }
            #pragma unroll
            for (int mt = 0; mt < 8; ++mt) {
                short8 afrag = *(const short8*)(W1rT + (16 * mt + l15) * 64 + 32 * ks + 8 * lg);
                accA[mt] = mfma16(afrag, bfrag, accA[mt]);
            }
        }
        #pragma unroll
        for (int mt = 0; mt < 8; ++mt) {
            f32x4 p4 = *(const f32x4*)(Pb + jrow * 128 + 16 * mt + 4 * lg);
            short4v o;
            #pragma unroll
            for (int r = 0; r < 4; ++r)
                o[r] = (short)f2bf(fmaxf(accA[mt][r] + p4[r], 0.f));
            *(short4v*)&sH[16 * wid + l15][16 * mt + 4 * lg] = o;
        }

        // phase B: H2^T[n][j] = relu(W2^T x H1^T + b2), K=128, in-place
        f32x4 accB[8];
        #pragma unroll
        for (int mt = 0; mt < 8; ++mt) accB[mt] = (f32x4)0.f;
        #pragma unroll
        for (int ks = 0; ks < 4; ++ks) {
            short8 bfrag = *(const short8*)(&sH[16 * wid + l15][32 * ks + 8 * lg]);
            #pragma unroll
            for (int mt = 0; mt < 8; ++mt) {
                short8 afrag = *(const short8*)(W2T + (16 * mt + l15) * 128 + 32 * ks + 8 * lg);
                accB[mt] = mfma16(afrag, bfrag, accB[mt]);
            }
        }
        #pragma unroll
        for (int mt = 0; mt < 8; ++mt) {
            f32x4 b2q = *(const f32x4*)(b2 + 16 * mt + 4 * lg);
            short4v o;
            #pragma unroll
            for (int r = 0; r < 4; ++r)
                o[r] = (short)f2bf(fmaxf(accB[mt][r] + b2q[r], 0.f));
            *(short4v*)&sH[16 * wid + l15][16 * mt + 4 * lg] = o;
        }

        // phase C: U[j][e] = H2 x W3 + b3, K=128 -> sUT[e][j] (4 consec j)
        f32x4 accC[4];
        #pragma unroll
        for (int ct = 0; ct < 4; ++ct) accC[ct] = (f32x4)0.f;
        #pragma unroll
        for (int ks = 0; ks < 4; ++ks) {
            short8 afrag = *(const short8*)(&sH[16 * wid + l15][32 * ks + 8 * lg]);
            #pragma unroll
            for (int ct = 0; ct < 4; ++ct) {
                short8 bfrag = *(const short8*)(W3T + (16 * ct + l15) * 128 + 32 * ks + 8 * lg);
                accC[ct] = mfma16(afrag, bfrag, accC[ct]);
            }
        }
        #pragma unroll
        for (int ct = 0; ct < 4; ++ct) {
            short4v o;
            #pragma unroll
            for (int r = 0; r < 4; ++r)
                o[r] = (short)f2bf(accC[ct][r] + b3v[ct]);
            *(short4v*)&sUT[16 * ct + l15][jc * 64 + 16 * wid + 4 * lg] = o;
        }
    }

    __syncthreads();   // sUT complete

    // ------- attention: D[e][i] per wave (64 i rows), K=256, both outputs -------
    const unsigned short* amap[2] = { AC + b * 65536, AQ + b * 65536 };
    const float* src[2]           = { rcb, rqb };
    float* dst[2] = { out_rc + bk * 16384, out_rq + bk * 16384 };
    const int i0 = 64 * wid;

    #pragma unroll
    for (int p = 0; p < 2; ++p) {
        f32x4 acc[4][4];   // [et][it]
        #pragma unroll
        for (int et = 0; et < 4; ++et)
            #pragma unroll
            for (int it = 0; it < 4; ++it) acc[et][it] = (f32x4)0.f;
        for (int ks = 0; ks < 8; ++ks) {
            short8 uf[4];
            #pragma unroll
            for (int et = 0; et < 4; ++et)
                uf[et] = *(const short8*)(&sUT[16 * et + l15][32 * ks + 8 * lg]);
            #pragma unroll
            for (int it = 0; it < 4; ++it) {
                short8 af = *(const short8*)(amap[p] + (i0 + 16 * it + l15) * 256 + 32 * ks + 8 * lg);
                #pragma unroll
                for (int et = 0; et < 4; ++et)
                    acc[et][it] = mfma16(uf[et], af, acc[et][it]);
            }
        }
        #pragma unroll
        for (int it = 0; it < 4; ++it) {
            #pragma unroll
            for (int et = 0; et < 4; ++et) {
                const int i = i0 + 16 * it + l15;
                const int e0 = 16 * et + 4 * lg;
                f32x4 rv = *(const f32x4*)(src[p] + i * 64 + e0);
                f32x4 o;
                #pragma unroll
                for (int r = 0; r < 4; ++r)
                    o[r] = rv[r] - ALPHA * acc[et][it][r];
                *(f32x4*)(dst[p] + i * 64 + e0) = o;
            }
        }
    }
}

extern "C" void kernel_launch(void* const* d_in, const int* in_sizes, int n_in,
                              void* d_out, int out_size, void* d_ws, size_t ws_size,
                              hipStream_t stream)
{
    const float* x   = (const float*)d_in[0];
    const float* y   = (const float*)d_in[1];
    const float* rc  = (const float*)d_in[2];
    const float* rq  = (const float*)d_in[3];
    const float* cat = (const float*)d_in[4];
    const float* qat = (const float*)d_in[5];
    const float* W1  = (const float*)d_in[6];
    const float* b1  = (const float*)d_in[7];
    const float* W2  = (const float*)d_in[8];
    const float* b2  = (const float*)d_in[9];
    const float* W3  = (const float*)d_in[10];
    const float* b3  = (const float*)d_in[11];

    float* out_rc = (float*)d_out;
    float* out_rq = out_rc + (size_t)4 * 256 * 256 * 64;
    unsigned char* ws = (unsigned char*)d_ws;

    prep_kernel<<<1152, 256, 0, stream>>>(x, y, cat, qat, W1, b1, W2, W3, ws);
    fused_kernel<<<dim3(256, 4), 256, 0, stream>>>(rc, rq, b2, b3, ws, out_rc, out_rq);
}

// Round 7
// 373.396 us; speedup vs baseline: 1.4307x; 1.4307x over previous
//
#include <hip/hip_runtime.h>
#include <hip/hip_bf16.h>

typedef __attribute__((ext_vector_type(8))) short  short8;
typedef __attribute__((ext_vector_type(4))) short  short4v;
typedef __attribute__((ext_vector_type(4))) float  f32x4;

#define ALPHA 0.1f

__device__ __forceinline__ unsigned short f2bf(float f) {
    unsigned int u = __float_as_uint(f);
    u = (u + 0x7FFFu + ((u >> 16) & 1u)) >> 16;   // RNE
    return (unsigned short)u;
}

__device__ __forceinline__ f32x4 mfma16(short8 a, short8 b, f32x4 c) {
    return __builtin_amdgcn_mfma_f32_16x16x32_bf16(a, b, c, 0, 0, 0);
}

// ---- ws layout (bytes) ----
// P:     float  [4][256][128]  = x@W1x + y@W1y + b1        (524288 B)
// W1rT:  ushort [128][64]      W1rT[h][e] = W1[96+e][h]    (16384 B)
// W2T:   ushort [128][128]     W2T[n][k]  = W2[k][n]       (32768 B)
// W3T:   ushort [64][128]      W3T[e][h]  = W3[h][e]       (16384 B)
// ATTC:  ushort [4][256][256]                              (524288 B)
// ATTQ:  ushort [4][256][256]                              (524288 B)
#define WS_P     0u
#define WS_W1RT  524288u
#define WS_W2T   540672u
#define WS_W3T   573440u
#define WS_ATTC  589824u
#define WS_ATTQ  1114112u

__global__ __launch_bounds__(256) void prep_kernel(
    const float* __restrict__ x, const float* __restrict__ y,
    const float* __restrict__ cat, const float* __restrict__ qat,
    const float* __restrict__ W1, const float* __restrict__ b1,
    const float* __restrict__ W2, const float* __restrict__ W3,
    unsigned char* __restrict__ ws)
{
    const unsigned int blk = blockIdx.x, tid = threadIdx.x;
    float* P = (float*)(ws + WS_P);
    unsigned short* W1rT = (unsigned short*)(ws + WS_W1RT);
    unsigned short* W2T  = (unsigned short*)(ws + WS_W2T);
    unsigned short* W3T  = (unsigned short*)(ws + WS_W3T);
    unsigned short* AC   = (unsigned short*)(ws + WS_ATTC);
    unsigned short* AQ   = (unsigned short*)(ws + WS_ATTQ);

    if (blk < 512u) {                          // P[b*256+j][h], 131072 threads
        unsigned int t = blk * 256u + tid;
        unsigned int h = t & 127u, bj = t >> 7;
        float acc = b1[h];
        const float* xp = x + bj * 64u;
        const float* yp = y + bj * 32u;
        #pragma unroll 8
        for (int d = 0; d < 64; ++d) acc += xp[d] * W1[d * 128 + h];
        #pragma unroll 8
        for (int d = 0; d < 32; ++d) acc += yp[d] * W1[(64 + d) * 128 + h];
        P[t] = acc;
    } else if (blk < 544u) {                   // W1rT (8192)
        unsigned int w = (blk - 512u) * 256u + tid;
        unsigned int h = w >> 6, e = w & 63u;
        W1rT[w] = f2bf(W1[(96u + e) * 128u + h]);
    } else if (blk < 608u) {                   // W2T (16384)
        unsigned int w = (blk - 544u) * 256u + tid;
        unsigned int n = w >> 7, k2 = w & 127u;
        W2T[w] = f2bf(W2[k2 * 128u + n]);
    } else if (blk < 640u) {                   // W3T (8192)
        unsigned int w = (blk - 608u) * 256u + tid;
        unsigned int e = w >> 7, h = w & 127u;
        W3T[w] = f2bf(W3[h * 64u + e]);
    } else if (blk < 896u) {                   // ATTC (65536 x4)
        unsigned int w = (blk - 640u) * 256u + tid;
        f32x4 v = *(const f32x4*)(cat + 4u * w);
        short4v o;
        #pragma unroll
        for (int i = 0; i < 4; ++i) o[i] = (short)f2bf(v[i]);
        *(short4v*)(AC + 4u * w) = o;
    } else {                                   // ATTQ (65536 x4)
        unsigned int w = (blk - 896u) * 256u + tid;
        f32x4 v = *(const f32x4*)(qat + 4u * w);
        short4v o;
        #pragma unroll
        for (int i = 0; i < 4; ++i) o[i] = (short)f2bf(v[i]);
        *(short4v*)(AQ + 4u * w) = o;
    }
}

// One block per (b,k). 4 waves. MLP phases computed transposed (D[h][j])
// so each lane's 4 acc values are 4 consecutive h -> ds_write_b64 + float4
// bias loads. Attention computed as D[e][i] (A=U^T from LDS, B=att map) so
// each lane's 4 acc values are 4 consecutive e -> float4 global load/store.
// NOTE: no min-waves bound — round-4 showed __launch_bounds__(256,3) forces
// VGPR 196->84 with a catastrophic scratch-spill storm (+590 MB HBM, 2x slower).
__global__ __launch_bounds__(256) void fused_kernel(
    const float* __restrict__ rc, const float* __restrict__ rq,
    const float* __restrict__ b2, const float* __restrict__ b3,
    const unsigned char* __restrict__ ws,
    float* __restrict__ out_rc, float* __restrict__ out_rq)
{
    const float* P = (const float*)(ws + WS_P);
    const unsigned short* W1rT = (const unsigned short*)(ws + WS_W1RT);
    const unsigned short* W2T  = (const unsigned short*)(ws + WS_W2T);
    const unsigned short* W3T  = (const unsigned short*)(ws + WS_W3T);
    const unsigned short* AC   = (const unsigned short*)(ws + WS_ATTC);
    const unsigned short* AQ   = (const unsigned short*)(ws + WS_ATTQ);

    __shared__ unsigned short sH[64][136];    // H strip, 272B row = 16B mult
    __shared__ unsigned short sUT[64][264];   // U^T [e][j], 528B row = 16B mult

    const int tid  = threadIdx.x;
    const int lane = tid & 63;
    const int wid  = tid >> 6;
    const int l15  = lane & 15;
    const int lg   = lane >> 4;
    const int b    = blockIdx.y;
    const int k    = blockIdx.x;

    const size_t bk = (size_t)(b * 256 + k);
    const float* rcb = rc + bk * (256 * 64);
    const float* rqb = rq + bk * (256 * 64);
    const float* Pb  = P + b * (256 * 128);

    float b3v[4];
    #pragma unroll
    for (int ct = 0; ct < 4; ++ct) b3v[ct] = b3[16 * ct + l15];

    // ---------------- MLP: 4 chunks of 64 rows ----------------
    for (int jc = 0; jc < 4; ++jc) {
        const int jrow = jc * 64 + 16 * wid + l15;   // this lane's j row

        // phase A: H1^T[h][j] = relu(W1r^T x rc^T + P^T), K=64
        f32x4 accA[8];
        #pragma unroll
        for (int mt = 0; mt < 8; ++mt) accA[mt] = (f32x4)0.f;
        #pragma unroll
        for (int ks = 0; ks < 2; ++ks) {
            const float* ap = rcb + jrow * 64 + 32 * ks + 8 * lg;
            f32x4 a0 = *(const f32x4*)ap;
            f32x4 a1 = *(const f32x4*)(ap + 4);
            short8 bfrag;
            #pragma unroll
            for (int i = 0; i < 4; ++i) {
                bfrag[i]     = (short)f2bf(a0[i]);
                bfrag[4 + i] = (short)f2bf(a1[i]);
            }
            #pragma unroll
            for (int mt = 0; mt < 8; ++mt) {
                short8 afrag = *(const short8*)(W1rT + (16 * mt + l15) * 64 + 32 * ks + 8 * lg);
                accA[mt] = mfma16(afrag, bfrag, accA[mt]);
            }
        }
        #pragma unroll
        for (int mt = 0; mt < 8; ++mt) {
            f32x4 p4 = *(const f32x4*)(Pb + jrow * 128 + 16 * mt + 4 * lg);
            short4v o;
            #pragma unroll
            for (int r = 0; r < 4; ++r)
                o[r] = (short)f2bf(fmaxf(accA[mt][r] + p4[r], 0.f));
            *(short4v*)&sH[16 * wid + l15][16 * mt + 4 * lg] = o;
        }

        // phase B: H2^T[n][j] = relu(W2^T x H1^T + b2), K=128, in-place
        f32x4 accB[8];
        #pragma unroll
        for (int mt = 0; mt < 8; ++mt) accB[mt] = (f32x4)0.f;
        #pragma unroll
        for (int ks = 0; ks < 4; ++ks) {
            short8 bfrag = *(const short8*)(&sH[16 * wid + l15][32 * ks + 8 * lg]);
            #pragma unroll
            for (int mt = 0; mt < 8; ++mt) {
                short8 afrag = *(const short8*)(W2T + (16 * mt + l15) * 128 + 32 * ks + 8 * lg);
                accB[mt] = mfma16(afrag, bfrag, accB[mt]);
            }
        }
        #pragma unroll
        for (int mt = 0; mt < 8; ++mt) {
            f32x4 b2q = *(const f32x4*)(b2 + 16 * mt + 4 * lg);
            short4v o;
            #pragma unroll
            for (int r = 0; r < 4; ++r)
                o[r] = (short)f2bf(fmaxf(accB[mt][r] + b2q[r], 0.f));
            *(short4v*)&sH[16 * wid + l15][16 * mt + 4 * lg] = o;
        }

        // phase C: U[j][e] = H2 x W3 + b3, K=128 -> sUT[e][j] (4 consec j)
        f32x4 accC[4];
        #pragma unroll
        for (int ct = 0; ct < 4; ++ct) accC[ct] = (f32x4)0.f;
        #pragma unroll
        for (int ks = 0; ks < 4; ++ks) {
            short8 afrag = *(const short8*)(&sH[16 * wid + l15][32 * ks + 8 * lg]);
            #pragma unroll
            for (int ct = 0; ct < 4; ++ct) {
                short8 bfrag = *(const short8*)(W3T + (16 * ct + l15) * 128 + 32 * ks + 8 * lg);
                accC[ct] = mfma16(afrag, bfrag, accC[ct]);
            }
        }
        #pragma unroll
        for (int ct = 0; ct < 4; ++ct) {
            short4v o;
            #pragma unroll
            for (int r = 0; r < 4; ++r)
                o[r] = (short)f2bf(accC[ct][r] + b3v[ct]);
            *(short4v*)&sUT[16 * ct + l15][jc * 64 + 16 * wid + 4 * lg] = o;
        }
    }

    __syncthreads();   // sUT complete

    // ------- attention: D[e][i] per wave (64 i rows), K=256, both outputs -------
    const unsigned short* amap[2] = { AC + b * 65536, AQ + b * 65536 };
    const float* src[2]           = { rcb, rqb };
    float* dst[2] = { out_rc + bk * 16384, out_rq + bk * 16384 };
    const int i0 = 64 * wid;

    #pragma unroll
    for (int p = 0; p < 2; ++p) {
        f32x4 acc[4][4];   // [et][it]
        #pragma unroll
        for (int et = 0; et < 4; ++et)
            #pragma unroll
            for (int it = 0; it < 4; ++it) acc[et][it] = (f32x4)0.f;
        for (int ks = 0; ks < 8; ++ks) {
            short8 uf[4];
            #pragma unroll
            for (int et = 0; et < 4; ++et)
                uf[et] = *(const short8*)(&sUT[16 * et + l15][32 * ks + 8 * lg]);
            #pragma unroll
            for (int it = 0; it < 4; ++it) {
                short8 af = *(const short8*)(amap[p] + (i0 + 16 * it + l15) * 256 + 32 * ks + 8 * lg);
                #pragma unroll
                for (int et = 0; et < 4; ++et)
                    acc[et][it] = mfma16(uf[et], af, acc[et][it]);
            }
        }
        #pragma unroll
        for (int it = 0; it < 4; ++it) {
            #pragma unroll
            for (int et = 0; et < 4; ++et) {
                const int i = i0 + 16 * it + l15;
                const int e0 = 16 * et + 4 * lg;
                f32x4 rv = *(const f32x4*)(src[p] + i * 64 + e0);
                f32x4 o;
                #pragma unroll
                for (int r = 0; r < 4; ++r)
                    o[r] = rv[r] - ALPHA * acc[et][it][r];
                *(f32x4*)(dst[p] + i * 64 + e0) = o;
            }
        }
    }
}

extern "C" void kernel_launch(void* const* d_in, const int* in_sizes, int n_in,
                              void* d_out, int out_size, void* d_ws, size_t ws_size,
                              hipStream_t stream)
{
    const float* x   = (const float*)d_in[0];
    const float* y   = (const float*)d_in[1];
    const float* rc  = (const float*)d_in[2];
    const float* rq  = (const float*)d_in[3];
    const float* cat = (const float*)d_in[4];
    const float* qat = (const float*)d_in[5];
    const float* W1  = (const float*)d_in[6];
    const float* b1  = (const float*)d_in[7];
    const float* W2  = (const float*)d_in[8];
    const float* b2  = (const float*)d_in[9];
    const float* W3  = (const float*)d_in[10];
    const float* b3  = (const float*)d_in[11];

    float* out_rc = (float*)d_out;
    float* out_rq = out_rc + (size_t)4 * 256 * 256 * 64;
    unsigned char* ws = (unsigned char*)d_ws;

    prep_kernel<<<1152, 256, 0, stream>>>(x, y, cat, qat, W1, b1, W2, W3, ws);
    fused_kernel<<<dim3(256, 4), 256, 0, stream>>>(rc, rq, b2, b3, ws, out_rc, out_rq);
}